// Round 1
// baseline (770.149 us; speedup 1.0000x reference)
//
#include <hip/hip_runtime.h>
#include <hip/hip_bf16.h>
#include <stdint.h>

#define E_EXP 8
#define TOK   4096
#define HD    768
#define FD    3072
#define BK    64
#define CAP   8320   // 8192 assignments + max per-expert tile padding

typedef __attribute__((ext_vector_type(8))) short bf16x8;
typedef __attribute__((ext_vector_type(4))) float f32x4;

__device__ __forceinline__ unsigned short f2bf(float f) {
  union { float f; unsigned u; } v; v.f = f;
  unsigned r = v.u + 0x7fffu + ((v.u >> 16) & 1u);
  return (unsigned short)(r >> 16);
}

__device__ __forceinline__ void gload_lds16(const void* g, void* l) {
  __builtin_amdgcn_global_load_lds(
      (const __attribute__((address_space(1))) unsigned int*)g,
      (__attribute__((address_space(3))) unsigned int*)l, 16, 0, 0);
}

// ---------------- router: scores, softmax, top-2, stats, x->bf16 ----------------
__global__ __launch_bounds__(256) void router_kernel(
    const float* __restrict__ x, const float* __restrict__ rw,
    const float* __restrict__ rb, unsigned short* __restrict__ xb,
    int* __restrict__ meta, float* __restrict__ probs_sum,
    int* __restrict__ ids, float* __restrict__ gates)
{
  __shared__ float lrw[E_EXP * HD];   // [e][h] to avoid bank conflicts
  for (int i = threadIdx.x; i < E_EXP * HD; i += 256) {
    int h = i >> 3, e = i & 7;
    lrw[e * HD + h] = rw[i];
  }
  __syncthreads();
  const int wave = threadIdx.x >> 6, lane = threadIdx.x & 63;
  const int t = blockIdx.x * 4 + wave;
  const float* xrow = x + (size_t)t * HD;
  float acc[8] = {0, 0, 0, 0, 0, 0, 0, 0};
#pragma unroll
  for (int i = 0; i < HD / 64; ++i) {
    int h = i * 64 + lane;
    float xv = xrow[h];
    xb[(size_t)t * HD + h] = f2bf(xv);
#pragma unroll
    for (int e = 0; e < 8; ++e) acc[e] += xv * lrw[e * HD + h];
  }
#pragma unroll
  for (int d = 1; d < 64; d <<= 1) {
#pragma unroll
    for (int e = 0; e < 8; ++e) acc[e] += __shfl_xor(acc[e], d);
  }
  float p[8]; float m = -1e30f, sum = 0.f;
#pragma unroll
  for (int e = 0; e < 8; ++e) { p[e] = acc[e] + rb[e]; m = fmaxf(m, p[e]); }
#pragma unroll
  for (int e = 0; e < 8; ++e) { p[e] = __expf(p[e] - m); sum += p[e]; }
  float inv = 1.f / sum;
#pragma unroll
  for (int e = 0; e < 8; ++e) p[e] *= inv;
  int i1 = 0;
#pragma unroll
  for (int e = 1; e < 8; ++e) if (p[e] > p[i1]) i1 = e;     // ties -> lower idx
  int i2 = (i1 == 0) ? 1 : 0;
#pragma unroll
  for (int e = 0; e < 8; ++e) if (e != i1 && p[e] > p[i2]) i2 = e;
  if (lane == 0) {
    ids[t * 2] = i1; ids[t * 2 + 1] = i2;
    float den = 1.f / (p[i1] + p[i2] + 1e-9f);
    gates[t * 2] = p[i1] * den; gates[t * 2 + 1] = p[i2] * den;
    atomicAdd(&meta[i1], 1);        // expert_count
    atomicAdd(&meta[i2], 1);
    atomicAdd(&meta[8 + i1], 1);    // top-1 counts for bal loss
#pragma unroll
    for (int e = 0; e < 8; ++e) atomicAdd(&probs_sum[e], p[e]);
  }
}

// ---------------- weight transpose: W[e][Kd][Nd] f32 -> Wt[e][Nd][Kd] bf16 ------
__global__ __launch_bounds__(256) void transpose_kernel(
    const float* __restrict__ W, unsigned short* __restrict__ Wt,
    int Kd, int Nd)
{
  __shared__ float tile[32][33];
  const int e = blockIdx.z;
  const int n0 = blockIdx.x * 32, k0 = blockIdx.y * 32;
  const int ci = threadIdx.x & 31, ri = threadIdx.x >> 5;
  const float* src = W + ((size_t)e * Kd + k0) * Nd + n0;
#pragma unroll
  for (int i = 0; i < 32; i += 8)
    tile[ri + i][ci] = src[(size_t)(ri + i) * Nd + ci];
  __syncthreads();
  unsigned short* dst = Wt + ((size_t)e * Nd + n0) * Kd + k0;
  const int co = (threadIdx.x & 15) * 2, ro = threadIdx.x >> 4;
#pragma unroll
  for (int i = 0; i < 32; i += 16) {
    int r = ro + i;
    unsigned v = (unsigned)f2bf(tile[co][r]) | ((unsigned)f2bf(tile[co + 1][r]) << 16);
    *(unsigned*)&dst[(size_t)r * Kd + co] = v;
  }
}

// ---------------- offsets / tile maps / balance loss ---------------------------
__global__ void offsets_kernel(int* meta, const float* probs_sum, float* loss_out)
{
  if (threadIdx.x != 0 || blockIdx.x != 0) return;
  int total = 0, nt1 = 0, nt2 = 0;
  for (int e = 0; e < 8; ++e) {
    int c = meta[e];
    meta[16 + e] = total;                       // base
    int t1 = (c + 127) >> 7;
    for (int i = 0; i < t1; ++i) { meta[64 + nt1 * 2] = e; meta[64 + nt1 * 2 + 1] = total + i * 128; ++nt1; }
    int t2 = (c + 63) >> 6;
    for (int i = 0; i < t2; ++i) { meta[256 + nt2 * 2] = e; meta[256 + nt2 * 2 + 1] = total + i * 64; ++nt2; }
    total += c;
  }
  meta[32] = nt1; meta[33] = nt2;
  float loss = 0.f;
  for (int e = 0; e < 8; ++e)
    loss += ((float)meta[8 + e] / 4096.f) * (probs_sum[e] / 4096.f);
  loss_out[0] = 0.001f * loss;
}

// ---------------- scatter tokens into compact per-expert lists ------------------
__global__ __launch_bounds__(256) void scatter_kernel(
    const int* __restrict__ ids, const float* __restrict__ gates,
    int* __restrict__ meta, int* __restrict__ token_list,
    float* __restrict__ gate_list)
{
  int t = blockIdx.x * 256 + threadIdx.x;
  if (t >= TOK) return;
#pragma unroll
  for (int k = 0; k < 2; ++k) {
    int e = ids[t * 2 + k];
    int slot = atomicAdd(&meta[24 + e], 1);
    int pos = meta[16 + e] + slot;
    token_list[pos] = t;
    gate_list[pos] = gates[t * 2 + k];
  }
}

// ---------------- grouped GEMM (MODE 0: x@w1 + relu^2 -> h1 bf16;
//                  MODE 1: h1@w2, gate-weighted atomicAdd into out) -------------
template<int BM, int BN, int MODE>
__global__ __launch_bounds__(256) void moe_gemm(
    const unsigned short* __restrict__ A,
    const unsigned short* __restrict__ Bw,   // [E][NN][Kdim] bf16 (pre-transposed)
    const float* __restrict__ bias,          // [E][NN]
    const int* __restrict__ token_list,
    const float* __restrict__ gate_list,
    const int* __restrict__ meta,
    unsigned short* __restrict__ h1out,
    float* __restrict__ out,
    const int Kdim, const int NN)
{
  const int nt_total = meta[32 + MODE];
  const int mt = blockIdx.x;
  if (mt >= nt_total) return;
  const int* tmap = meta + (MODE == 0 ? 64 : 256);
  const int e = tmap[mt * 2], arow0 = tmap[mt * 2 + 1];
  const int ne_end = meta[16 + e] + meta[e];
  const int n0 = blockIdx.y * BN;

  __shared__ unsigned short lA[BM * BK];
  __shared__ unsigned short lB[BN * BK];

  const int tid = threadIdx.x;
  const int wave = tid >> 6, lane = tid & 63;
  const int wr = wave >> 1, wc = wave & 1;
  constexpr int FM = BM / 32, FN = BN / 32;
  constexpr int NCA = BM / 32;   // A 1KB-chunks per wave (BM/8 total / 4 waves)
  constexpr int NCB = BN / 32;   // B chunks per wave

  size_t aSrc[NCA];
#pragma unroll
  for (int i = 0; i < NCA; ++i) {
    int c = wave + i * 4;
    int r = c * 8 + (lane >> 3);
    int grow = (MODE == 0) ? token_list[arow0 + r] : (arow0 + r);
    aSrc[i] = (size_t)grow * Kdim + (lane & 7) * 8;
  }
  size_t bSrc[NCB];
#pragma unroll
  for (int i = 0; i < NCB; ++i) {
    int c = wave + i * 4;
    int n = n0 + c * 8 + (lane >> 3);
    bSrc[i] = ((size_t)e * NN + n) * Kdim + (lane & 7) * 8;
  }

  f32x4 acc[FM][FN] = {};

  for (int k0 = 0; k0 < Kdim; k0 += BK) {
#pragma unroll
    for (int i = 0; i < NCA; ++i)
      gload_lds16(A + aSrc[i] + k0, &lA[(wave + i * 4) * 512]);
#pragma unroll
    for (int i = 0; i < NCB; ++i)
      gload_lds16(Bw + bSrc[i] + k0, &lB[(wave + i * 4) * 512]);
    __syncthreads();
#pragma unroll
    for (int kk = 0; kk < BK; kk += 32) {
      bf16x8 af[FM], bfr[FN];
      const int kpos = kk + (lane >> 4) * 8;
#pragma unroll
      for (int m2 = 0; m2 < FM; ++m2) {
        int row = wr * (BM / 2) + m2 * 16 + (lane & 15);
        af[m2] = *(const bf16x8*)&lA[row * BK + kpos];
      }
#pragma unroll
      for (int n2 = 0; n2 < FN; ++n2) {
        int row = wc * (BN / 2) + n2 * 16 + (lane & 15);
        bfr[n2] = *(const bf16x8*)&lB[row * BK + kpos];
      }
#pragma unroll
      for (int m2 = 0; m2 < FM; ++m2)
#pragma unroll
        for (int n2 = 0; n2 < FN; ++n2)
          acc[m2][n2] = __builtin_amdgcn_mfma_f32_16x16x32_bf16(
              af[m2], bfr[n2], acc[m2][n2], 0, 0, 0);
    }
    __syncthreads();
  }

  const float* be = bias + (size_t)e * NN;
#pragma unroll
  for (int m2 = 0; m2 < FM; ++m2) {
    const int lr = wr * (BM / 2) + m2 * 16 + (lane >> 4) * 4;
#pragma unroll
    for (int n2 = 0; n2 < FN; ++n2) {
      const int col = n0 + wc * (BN / 2) + n2 * 16 + (lane & 15);
      const float bv = be[col];
#pragma unroll
      for (int j = 0; j < 4; ++j) {
        const int arow = arow0 + lr + j;
        if (arow < ne_end) {
          float v = acc[m2][n2][j] + bv;
          if (MODE == 0) {
            v = fmaxf(v, 0.f); v = v * v;
            h1out[(size_t)arow * NN + col] = f2bf(v);
          } else {
            int t = token_list[arow];
            float g = gate_list[arow];
            atomicAdd(&out[(size_t)t * NN + col], g * v);
          }
        }
      }
    }
  }
}

// -------------------------------- launch ---------------------------------------
extern "C" void kernel_launch(void* const* d_in, const int* in_sizes, int n_in,
                              void* d_out, int out_size, void* d_ws, size_t ws_size,
                              hipStream_t stream)
{
  (void)in_sizes; (void)n_in; (void)ws_size;
  const float* x  = (const float*)d_in[0];
  const float* rw = (const float*)d_in[1];
  const float* rb = (const float*)d_in[2];
  const float* w1 = (const float*)d_in[3];
  const float* b1 = (const float*)d_in[4];
  const float* w2 = (const float*)d_in[5];
  const float* b2 = (const float*)d_in[6];
  float* out = (float*)d_out;

  char* ws = (char*)d_ws;
  size_t off = 0;
  auto alloc = [&](size_t bytes) {
    off = (off + 255) & ~(size_t)255;
    void* p = ws + off;
    off += bytes;
    return p;
  };
  unsigned short* xb  = (unsigned short*)alloc((size_t)TOK * HD * 2);
  unsigned short* w1t = (unsigned short*)alloc((size_t)E_EXP * FD * HD * 2);
  unsigned short* w2t = (unsigned short*)alloc((size_t)E_EXP * HD * FD * 2);
  unsigned short* h1  = (unsigned short*)alloc((size_t)CAP * FD * 2);
  int*   token_list = (int*)alloc(CAP * 4);
  float* gate_list  = (float*)alloc(CAP * 4);
  int*   ids        = (int*)alloc((size_t)TOK * 2 * 4);
  float* gates      = (float*)alloc((size_t)TOK * 2 * 4);
  int*   meta       = (int*)alloc(1024 * 4);
  float* probs_sum  = (float*)alloc(256);
  char*  ctrl       = (char*)token_list;
  size_t ctrl_bytes = (ws + off) - ctrl;

  hipMemsetAsync(d_out, 0, (size_t)out_size * 4, stream);
  hipMemsetAsync(ctrl, 0, ctrl_bytes, stream);

  router_kernel<<<TOK / 4, 256, 0, stream>>>(x, rw, rb, xb, meta, probs_sum, ids, gates);
  transpose_kernel<<<dim3(FD / 32, HD / 32, E_EXP), 256, 0, stream>>>(w1, w1t, HD, FD);
  transpose_kernel<<<dim3(HD / 32, FD / 32, E_EXP), 256, 0, stream>>>(w2, w2t, FD, HD);
  offsets_kernel<<<1, 64, 0, stream>>>(meta, probs_sum, out + (size_t)TOK * HD);
  scatter_kernel<<<TOK / 256, 256, 0, stream>>>(ids, gates, meta, token_list, gate_list);
  moe_gemm<128, 128, 0><<<dim3(71, FD / 128), 256, 0, stream>>>(
      xb, w1t, b1, token_list, gate_list, meta, h1, nullptr, HD, FD);
  moe_gemm<64, 128, 1><<<dim3(135, HD / 128), 256, 0, stream>>>(
      h1, w2t, b2, token_list, gate_list, meta, nullptr, out, FD, HD);
}

// Round 2
// 323.079 us; speedup vs baseline: 2.3838x; 2.3838x over previous
//
#include <hip/hip_runtime.h>
#include <hip/hip_bf16.h>
#include <stdint.h>

#define E_EXP 8
#define TOK   4096
#define HD    768
#define FD    3072
#define BK    64
#define CAP   8320   // 8192 assignments + max per-expert tile padding

typedef __attribute__((ext_vector_type(8))) short bf16x8;
typedef __attribute__((ext_vector_type(4))) float f32x4;

__device__ __forceinline__ unsigned short f2bf(float f) {
  union { float f; unsigned u; } v; v.f = f;
  unsigned r = v.u + 0x7fffu + ((v.u >> 16) & 1u);
  return (unsigned short)(r >> 16);
}

__device__ __forceinline__ void gload_lds16(const void* g, void* l) {
  __builtin_amdgcn_global_load_lds(
      (const __attribute__((address_space(1))) unsigned int*)g,
      (__attribute__((address_space(3))) unsigned int*)l, 16, 0, 0);
}

// ---------------- router: scores, softmax, top-2, x->bf16; NO atomics ----------
__global__ __launch_bounds__(256) void router_kernel(
    const float* __restrict__ x, const float* __restrict__ rw,
    const float* __restrict__ rb, unsigned short* __restrict__ xb,
    float* __restrict__ probs, int* __restrict__ ids,
    float* __restrict__ gates)
{
  __shared__ float lrw[E_EXP * HD];   // [e][h]
  for (int i = threadIdx.x; i < E_EXP * HD; i += 256) {
    int h = i >> 3, e = i & 7;
    lrw[e * HD + h] = rw[i];
  }
  __syncthreads();
  const int wave = threadIdx.x >> 6, lane = threadIdx.x & 63;
  const int t = blockIdx.x * 4 + wave;
  const float* xrow = x + (size_t)t * HD;
  float acc[8] = {0, 0, 0, 0, 0, 0, 0, 0};
#pragma unroll
  for (int i = 0; i < HD / 64; ++i) {
    int h = i * 64 + lane;
    float xv = xrow[h];
    xb[(size_t)t * HD + h] = f2bf(xv);
#pragma unroll
    for (int e = 0; e < 8; ++e) acc[e] += xv * lrw[e * HD + h];
  }
#pragma unroll
  for (int d = 1; d < 64; d <<= 1) {
#pragma unroll
    for (int e = 0; e < 8; ++e) acc[e] += __shfl_xor(acc[e], d);
  }
  if (lane == 0) {
    float p[8]; float m = -1e30f, sum = 0.f;
#pragma unroll
    for (int e = 0; e < 8; ++e) { p[e] = acc[e] + rb[e]; m = fmaxf(m, p[e]); }
#pragma unroll
    for (int e = 0; e < 8; ++e) { p[e] = __expf(p[e] - m); sum += p[e]; }
    float inv = 1.f / sum;
#pragma unroll
    for (int e = 0; e < 8; ++e) p[e] *= inv;
    int i1 = 0;
#pragma unroll
    for (int e = 1; e < 8; ++e) if (p[e] > p[i1]) i1 = e;   // ties -> lower idx
    int i2 = (i1 == 0) ? 1 : 0;
#pragma unroll
    for (int e = 0; e < 8; ++e) if (e != i1 && p[e] > p[i2]) i2 = e;
    ids[t * 2] = i1; ids[t * 2 + 1] = i2;
    float den = 1.f / (p[i1] + p[i2] + 1e-9f);
    gates[t * 2] = p[i1] * den; gates[t * 2 + 1] = p[i2] * den;
#pragma unroll
    for (int e = 0; e < 8; ++e) probs[t * 8 + e] = p[e];
  }
}

// ---------------- weight transpose: W[e][Kd][Nd] f32 -> Wt[e][Nd][Kd] bf16 ------
__global__ __launch_bounds__(256) void transpose_kernel(
    const float* __restrict__ W, unsigned short* __restrict__ Wt,
    int Kd, int Nd)
{
  __shared__ float tile[32][33];
  const int e = blockIdx.z;
  const int n0 = blockIdx.x * 32, k0 = blockIdx.y * 32;
  const int ci = threadIdx.x & 31, ri = threadIdx.x >> 5;
  const float* src = W + ((size_t)e * Kd + k0) * Nd + n0;
#pragma unroll
  for (int i = 0; i < 32; i += 8)
    tile[ri + i][ci] = src[(size_t)(ri + i) * Nd + ci];
  __syncthreads();
  unsigned short* dst = Wt + ((size_t)e * Nd + n0) * Kd + k0;
  const int co = (threadIdx.x & 15) * 2, ro = threadIdx.x >> 4;
#pragma unroll
  for (int i = 0; i < 32; i += 16) {
    int r = ro + i;
    unsigned v = (unsigned)f2bf(tile[co][r]) | ((unsigned)f2bf(tile[co + 1][r]) << 16);
    *(unsigned*)&dst[(size_t)r * Kd + co] = v;
  }
}

// ---------------- stats: counts, probs_sum, bases, tile maps, bal loss ----------
__global__ __launch_bounds__(256) void stats_kernel(
    const int* __restrict__ ids, const float* __restrict__ probs,
    int* __restrict__ meta, float* __restrict__ loss_out)
{
  __shared__ int cnt[8], top1c[8];
  __shared__ float wsum[4][8];
  if (threadIdx.x < 8) { cnt[threadIdx.x] = 0; top1c[threadIdx.x] = 0; }
  __syncthreads();
  float local[8] = {0, 0, 0, 0, 0, 0, 0, 0};
  for (int t = threadIdx.x; t < TOK; t += 256) {
    int e0 = ids[2 * t], e1 = ids[2 * t + 1];
    atomicAdd(&cnt[e0], 1); atomicAdd(&cnt[e1], 1); atomicAdd(&top1c[e0], 1);
    const float4* pr = (const float4*)&probs[(size_t)t * 8];
    float4 a = pr[0], b = pr[1];
    local[0] += a.x; local[1] += a.y; local[2] += a.z; local[3] += a.w;
    local[4] += b.x; local[5] += b.y; local[6] += b.z; local[7] += b.w;
  }
#pragma unroll
  for (int d = 1; d < 64; d <<= 1) {
#pragma unroll
    for (int e = 0; e < 8; ++e) local[e] += __shfl_xor(local[e], d);
  }
  const int wave = threadIdx.x >> 6, lane = threadIdx.x & 63;
  if (lane == 0) {
#pragma unroll
    for (int e = 0; e < 8; ++e) wsum[wave][e] = local[e];
  }
  __syncthreads();
  if (threadIdx.x == 0) {
    int total = 0, nt1 = 0, nt2 = 0;
    for (int e = 0; e < 8; ++e) {
      int c = cnt[e];
      meta[e] = c;
      meta[16 + e] = total;                     // base
      int t1 = (c + 127) >> 7;
      for (int i = 0; i < t1; ++i) { meta[64 + nt1 * 2] = e; meta[64 + nt1 * 2 + 1] = total + i * 128; ++nt1; }
      int t2 = (c + 63) >> 6;
      for (int i = 0; i < t2; ++i) { meta[256 + nt2 * 2] = e; meta[256 + nt2 * 2 + 1] = total + i * 64; ++nt2; }
      total += c;
    }
    meta[32] = nt1; meta[33] = nt2;
    float loss = 0.f;
    for (int e = 0; e < 8; ++e) {
      float psum = wsum[0][e] + wsum[1][e] + wsum[2][e] + wsum[3][e];
      loss += ((float)top1c[e] / 4096.f) * (psum / 4096.f);
    }
    loss_out[0] = 0.001f * loss;
  }
}

// ---------------- scatter: block-aggregated (128 global atomics total) ----------
__global__ __launch_bounds__(256) void scatter_kernel(
    const int* __restrict__ ids, const float* __restrict__ gates,
    int* __restrict__ meta, int* __restrict__ token_list,
    float* __restrict__ gate_list)
{
  __shared__ int lcnt[8];
  __shared__ int lbase[8];
  if (threadIdx.x < 8) lcnt[threadIdx.x] = 0;
  __syncthreads();
  const int t = blockIdx.x * 256 + threadIdx.x;
  const int e0 = ids[t * 2], e1 = ids[t * 2 + 1];
  const int s0 = atomicAdd(&lcnt[e0], 1);
  const int s1 = atomicAdd(&lcnt[e1], 1);
  __syncthreads();
  if (threadIdx.x < 8)
    lbase[threadIdx.x] = atomicAdd(&meta[24 + threadIdx.x], lcnt[threadIdx.x]);
  __syncthreads();
  int p0 = meta[16 + e0] + lbase[e0] + s0;
  int p1 = meta[16 + e1] + lbase[e1] + s1;
  token_list[p0] = t; gate_list[p0] = gates[t * 2];
  token_list[p1] = t; gate_list[p1] = gates[t * 2 + 1];
}

// ---------------- grouped GEMM (MODE 0: x@w1 + relu^2 -> h1 bf16;
//                  MODE 1: h1@w2, gate-weighted atomicAdd into out) -------------
template<int BM, int BN, int MODE>
__global__ __launch_bounds__(256) void moe_gemm(
    const unsigned short* __restrict__ A,
    const unsigned short* __restrict__ Bw,   // [E][NN][Kdim] bf16 (pre-transposed)
    const float* __restrict__ bias,          // [E][NN]
    const int* __restrict__ token_list,
    const float* __restrict__ gate_list,
    const int* __restrict__ meta,
    unsigned short* __restrict__ h1out,
    float* __restrict__ out,
    const int Kdim, const int NN)
{
  const int nt_total = meta[32 + MODE];
  const int mt = blockIdx.x;
  if (mt >= nt_total) return;
  const int* tmap = meta + (MODE == 0 ? 64 : 256);
  const int e = tmap[mt * 2], arow0 = tmap[mt * 2 + 1];
  const int ne_end = meta[16 + e] + meta[e];
  const int n0 = blockIdx.y * BN;

  __shared__ unsigned short lA[BM * BK];
  __shared__ unsigned short lB[BN * BK];

  const int tid = threadIdx.x;
  const int wave = tid >> 6, lane = tid & 63;
  const int wr = wave >> 1, wc = wave & 1;
  constexpr int FM = BM / 32, FN = BN / 32;
  constexpr int NCA = BM / 32;   // A 1KB-chunks per wave
  constexpr int NCB = BN / 32;   // B chunks per wave

  size_t aSrc[NCA];
#pragma unroll
  for (int i = 0; i < NCA; ++i) {
    int c = wave + i * 4;
    int r = c * 8 + (lane >> 3);
    int grow = (MODE == 0) ? token_list[arow0 + r] : (arow0 + r);
    aSrc[i] = (size_t)grow * Kdim + (lane & 7) * 8;
  }
  size_t bSrc[NCB];
#pragma unroll
  for (int i = 0; i < NCB; ++i) {
    int c = wave + i * 4;
    int n = n0 + c * 8 + (lane >> 3);
    bSrc[i] = ((size_t)e * NN + n) * Kdim + (lane & 7) * 8;
  }

  f32x4 acc[FM][FN] = {};

  for (int k0 = 0; k0 < Kdim; k0 += BK) {
#pragma unroll
    for (int i = 0; i < NCA; ++i)
      gload_lds16(A + aSrc[i] + k0, &lA[(wave + i * 4) * 512]);
#pragma unroll
    for (int i = 0; i < NCB; ++i)
      gload_lds16(Bw + bSrc[i] + k0, &lB[(wave + i * 4) * 512]);
    __syncthreads();
#pragma unroll
    for (int kk = 0; kk < BK; kk += 32) {
      bf16x8 af[FM], bfr[FN];
      const int kpos = kk + (lane >> 4) * 8;
#pragma unroll
      for (int m2 = 0; m2 < FM; ++m2) {
        int row = wr * (BM / 2) + m2 * 16 + (lane & 15);
        af[m2] = *(const bf16x8*)&lA[row * BK + kpos];
      }
#pragma unroll
      for (int n2 = 0; n2 < FN; ++n2) {
        int row = wc * (BN / 2) + n2 * 16 + (lane & 15);
        bfr[n2] = *(const bf16x8*)&lB[row * BK + kpos];
      }
#pragma unroll
      for (int m2 = 0; m2 < FM; ++m2)
#pragma unroll
        for (int n2 = 0; n2 < FN; ++n2)
          acc[m2][n2] = __builtin_amdgcn_mfma_f32_16x16x32_bf16(
              af[m2], bfr[n2], acc[m2][n2], 0, 0, 0);
    }
    __syncthreads();
  }

  const float* be = bias + (size_t)e * NN;
#pragma unroll
  for (int m2 = 0; m2 < FM; ++m2) {
    const int lr = wr * (BM / 2) + m2 * 16 + (lane >> 4) * 4;
#pragma unroll
    for (int n2 = 0; n2 < FN; ++n2) {
      const int col = n0 + wc * (BN / 2) + n2 * 16 + (lane & 15);
      const float bv = be[col];
#pragma unroll
      for (int j = 0; j < 4; ++j) {
        const int arow = arow0 + lr + j;
        if (arow < ne_end) {
          float v = acc[m2][n2][j] + bv;
          if (MODE == 0) {
            v = fmaxf(v, 0.f); v = v * v;
            h1out[(size_t)arow * NN + col] = f2bf(v);
          } else {
            int t = token_list[arow];
            float g = gate_list[arow];
            atomicAdd(&out[(size_t)t * NN + col], g * v);
          }
        }
      }
    }
  }
}

// -------------------------------- launch ---------------------------------------
extern "C" void kernel_launch(void* const* d_in, const int* in_sizes, int n_in,
                              void* d_out, int out_size, void* d_ws, size_t ws_size,
                              hipStream_t stream)
{
  (void)in_sizes; (void)n_in; (void)ws_size;
  const float* x  = (const float*)d_in[0];
  const float* rw = (const float*)d_in[1];
  const float* rb = (const float*)d_in[2];
  const float* w1 = (const float*)d_in[3];
  const float* b1 = (const float*)d_in[4];
  const float* w2 = (const float*)d_in[5];
  const float* b2 = (const float*)d_in[6];
  float* out = (float*)d_out;

  char* ws = (char*)d_ws;
  size_t off = 0;
  auto alloc = [&](size_t bytes) {
    off = (off + 255) & ~(size_t)255;
    void* p = ws + off;
    off += bytes;
    return p;
  };
  unsigned short* xb  = (unsigned short*)alloc((size_t)TOK * HD * 2);
  unsigned short* w1t = (unsigned short*)alloc((size_t)E_EXP * FD * HD * 2);
  unsigned short* w2t = (unsigned short*)alloc((size_t)E_EXP * HD * FD * 2);
  unsigned short* h1  = (unsigned short*)alloc((size_t)CAP * FD * 2);
  int*   token_list = (int*)alloc(CAP * 4);
  float* gate_list  = (float*)alloc(CAP * 4);
  int*   ids        = (int*)alloc((size_t)TOK * 2 * 4);
  float* gates      = (float*)alloc((size_t)TOK * 2 * 4);
  float* probs      = (float*)alloc((size_t)TOK * 8 * 4);
  int*   meta       = (int*)alloc(1024 * 4);
  char*  ctrl       = (char*)token_list;
  size_t ctrl_bytes = (ws + off) - ctrl;

  hipMemsetAsync(d_out, 0, (size_t)out_size * 4, stream);
  hipMemsetAsync(ctrl, 0, ctrl_bytes, stream);

  router_kernel<<<TOK / 4, 256, 0, stream>>>(x, rw, rb, xb, probs, ids, gates);
  transpose_kernel<<<dim3(FD / 32, HD / 32, E_EXP), 256, 0, stream>>>(w1, w1t, HD, FD);
  transpose_kernel<<<dim3(HD / 32, FD / 32, E_EXP), 256, 0, stream>>>(w2, w2t, FD, HD);
  stats_kernel<<<1, 256, 0, stream>>>(ids, probs, meta, out + (size_t)TOK * HD);
  scatter_kernel<<<TOK / 256, 256, 0, stream>>>(ids, gates, meta, token_list, gate_list);
  moe_gemm<128, 128, 0><<<dim3(71, FD / 128), 256, 0, stream>>>(
      xb, w1t, b1, token_list, gate_list, meta, h1, nullptr, HD, FD);
  moe_gemm<64, 128, 1><<<dim3(135, HD / 128), 256, 0, stream>>>(
      h1, w2t, b2, token_list, gate_list, meta, nullptr, out, FD, HD);
}

// Round 3
// 264.674 us; speedup vs baseline: 2.9098x; 1.2207x over previous
//
#include <hip/hip_runtime.h>
#include <hip/hip_bf16.h>
#include <stdint.h>

#define E_EXP 8
#define TOK   4096
#define HD    768
#define FD    3072
#define BK    64
#define CAP   8320   // 8192 assignments + max per-expert tile padding

typedef __attribute__((ext_vector_type(8))) short bf16x8;
typedef __attribute__((ext_vector_type(4))) float f32x4;

__device__ __forceinline__ unsigned short f2bf(float f) {
  union { float f; unsigned u; } v; v.f = f;
  unsigned r = v.u + 0x7fffu + ((v.u >> 16) & 1u);
  return (unsigned short)(r >> 16);
}
__device__ __forceinline__ float bf2f(unsigned short u) {
  union { unsigned u; float f; } v; v.u = ((unsigned)u) << 16;
  return v.f;
}

__device__ __forceinline__ void gload_lds16(const void* g, void* l) {
  __builtin_amdgcn_global_load_lds(
      (const __attribute__((address_space(1))) unsigned int*)g,
      (__attribute__((address_space(3))) unsigned int*)l, 16, 0, 0);
}

// ---------------- router: scores, softmax, top-2, x->bf16; NO atomics ----------
__global__ __launch_bounds__(256) void router_kernel(
    const float* __restrict__ x, const float* __restrict__ rw,
    const float* __restrict__ rb, unsigned short* __restrict__ xb,
    float* __restrict__ probs, int* __restrict__ ids,
    float* __restrict__ gates)
{
  __shared__ float lrw[E_EXP * HD];   // [e][h]
  for (int i = threadIdx.x; i < E_EXP * HD; i += 256) {
    int h = i >> 3, e = i & 7;
    lrw[e * HD + h] = rw[i];
  }
  __syncthreads();
  const int wave = threadIdx.x >> 6, lane = threadIdx.x & 63;
  const int t = blockIdx.x * 4 + wave;
  const float* xrow = x + (size_t)t * HD;
  float acc[8] = {0, 0, 0, 0, 0, 0, 0, 0};
#pragma unroll
  for (int i = 0; i < HD / 64; ++i) {
    int h = i * 64 + lane;
    float xv = xrow[h];
    xb[(size_t)t * HD + h] = f2bf(xv);
#pragma unroll
    for (int e = 0; e < 8; ++e) acc[e] += xv * lrw[e * HD + h];
  }
#pragma unroll
  for (int d = 1; d < 64; d <<= 1) {
#pragma unroll
    for (int e = 0; e < 8; ++e) acc[e] += __shfl_xor(acc[e], d);
  }
  if (lane == 0) {
    float p[8]; float m = -1e30f, sum = 0.f;
#pragma unroll
    for (int e = 0; e < 8; ++e) { p[e] = acc[e] + rb[e]; m = fmaxf(m, p[e]); }
#pragma unroll
    for (int e = 0; e < 8; ++e) { p[e] = __expf(p[e] - m); sum += p[e]; }
    float inv = 1.f / sum;
#pragma unroll
    for (int e = 0; e < 8; ++e) p[e] *= inv;
    int i1 = 0;
#pragma unroll
    for (int e = 1; e < 8; ++e) if (p[e] > p[i1]) i1 = e;   // ties -> lower idx
    int i2 = (i1 == 0) ? 1 : 0;
#pragma unroll
    for (int e = 0; e < 8; ++e) if (e != i1 && p[e] > p[i2]) i2 = e;
    ids[t * 2] = i1; ids[t * 2 + 1] = i2;
    float den = 1.f / (p[i1] + p[i2] + 1e-9f);
    gates[t * 2] = p[i1] * den; gates[t * 2 + 1] = p[i2] * den;
#pragma unroll
    for (int e = 0; e < 8; ++e) probs[t * 8 + e] = p[e];
  }
}

// ---------------- weight transpose: W[e][Kd][Nd] f32 -> Wt[e][Nd][Kd] bf16 ------
__global__ __launch_bounds__(256) void transpose_kernel(
    const float* __restrict__ W, unsigned short* __restrict__ Wt,
    int Kd, int Nd)
{
  __shared__ float tile[32][33];
  const int e = blockIdx.z;
  const int n0 = blockIdx.x * 32, k0 = blockIdx.y * 32;
  const int ci = threadIdx.x & 31, ri = threadIdx.x >> 5;
  const float* src = W + ((size_t)e * Kd + k0) * Nd + n0;
#pragma unroll
  for (int i = 0; i < 32; i += 8)
    tile[ri + i][ci] = src[(size_t)(ri + i) * Nd + ci];
  __syncthreads();
  unsigned short* dst = Wt + ((size_t)e * Nd + n0) * Kd + k0;
  const int co = (threadIdx.x & 15) * 2, ro = threadIdx.x >> 4;
#pragma unroll
  for (int i = 0; i < 32; i += 16) {
    int r = ro + i;
    unsigned v = (unsigned)f2bf(tile[co][r]) | ((unsigned)f2bf(tile[co + 1][r]) << 16);
    *(unsigned*)&dst[(size_t)r * Kd + co] = v;
  }
}

// ---------------- stats: counts, probs_sum, bases, tile maps, bal loss ----------
__global__ __launch_bounds__(256) void stats_kernel(
    const int* __restrict__ ids, const float* __restrict__ probs,
    int* __restrict__ meta, float* __restrict__ loss_out)
{
  __shared__ int cnt[8], top1c[8];
  __shared__ float wsum[4][8];
  if (threadIdx.x < 8) { cnt[threadIdx.x] = 0; top1c[threadIdx.x] = 0; }
  __syncthreads();
  float local[8] = {0, 0, 0, 0, 0, 0, 0, 0};
  for (int t = threadIdx.x; t < TOK; t += 256) {
    int e0 = ids[2 * t], e1 = ids[2 * t + 1];
    atomicAdd(&cnt[e0], 1); atomicAdd(&cnt[e1], 1); atomicAdd(&top1c[e0], 1);
    const float4* pr = (const float4*)&probs[(size_t)t * 8];
    float4 a = pr[0], b = pr[1];
    local[0] += a.x; local[1] += a.y; local[2] += a.z; local[3] += a.w;
    local[4] += b.x; local[5] += b.y; local[6] += b.z; local[7] += b.w;
  }
#pragma unroll
  for (int d = 1; d < 64; d <<= 1) {
#pragma unroll
    for (int e = 0; e < 8; ++e) local[e] += __shfl_xor(local[e], d);
  }
  const int wave = threadIdx.x >> 6, lane = threadIdx.x & 63;
  if (lane == 0) {
#pragma unroll
    for (int e = 0; e < 8; ++e) wsum[wave][e] = local[e];
  }
  __syncthreads();
  if (threadIdx.x == 0) {
    int total = 0, nt1 = 0, nt2 = 0;
    for (int e = 0; e < 8; ++e) {
      int c = cnt[e];
      meta[e] = c;
      meta[16 + e] = total;                     // base
      int t1 = (c + 127) >> 7;
      for (int i = 0; i < t1; ++i) { meta[64 + nt1 * 2] = e; meta[64 + nt1 * 2 + 1] = total + i * 128; ++nt1; }
      int t2 = (c + 63) >> 6;
      for (int i = 0; i < t2; ++i) { meta[256 + nt2 * 2] = e; meta[256 + nt2 * 2 + 1] = total + i * 64; ++nt2; }
      total += c;
    }
    meta[32] = nt1; meta[33] = nt2;
    float loss = 0.f;
    for (int e = 0; e < 8; ++e) {
      float psum = wsum[0][e] + wsum[1][e] + wsum[2][e] + wsum[3][e];
      loss += ((float)top1c[e] / 4096.f) * (psum / 4096.f);
    }
    loss_out[0] = 0.001f * loss;
  }
}

// ---------------- scatter: block-aggregated; records pos for combine -----------
__global__ __launch_bounds__(256) void scatter_kernel(
    const int* __restrict__ ids, int* __restrict__ meta,
    int* __restrict__ token_list, int* __restrict__ pos_list)
{
  __shared__ int lcnt[8];
  __shared__ int lbase[8];
  if (threadIdx.x < 8) lcnt[threadIdx.x] = 0;
  __syncthreads();
  const int t = blockIdx.x * 256 + threadIdx.x;
  const int e0 = ids[t * 2], e1 = ids[t * 2 + 1];
  const int s0 = atomicAdd(&lcnt[e0], 1);
  const int s1 = atomicAdd(&lcnt[e1], 1);
  __syncthreads();
  if (threadIdx.x < 8)
    lbase[threadIdx.x] = atomicAdd(&meta[24 + threadIdx.x], lcnt[threadIdx.x]);
  __syncthreads();
  int p0 = meta[16 + e0] + lbase[e0] + s0;
  int p1 = meta[16 + e1] + lbase[e1] + s1;
  token_list[p0] = t; pos_list[t * 2] = p0;
  token_list[p1] = t; pos_list[t * 2 + 1] = p1;
}

// ---------------- grouped GEMM (MODE 0: x@w1 + relu^2 -> h1 bf16;
//                  MODE 1: h1@w2 + b2 -> h2 bf16 rows) -------------------------
// LDS layout: linear rows of BK=64 bf16 (128 B); k-chunk (16 B) XOR-swizzled by
// (row&7) on BOTH the global source address (staging) and the ds_read address.
template<int BM, int BN, int MODE>
__global__ __launch_bounds__(256) void moe_gemm(
    const unsigned short* __restrict__ A,
    const unsigned short* __restrict__ Bw,   // [E][NN][Kdim] bf16 (pre-transposed)
    const float* __restrict__ bias,          // [E][NN]
    const int* __restrict__ token_list,
    const int* __restrict__ meta,
    unsigned short* __restrict__ Cout,       // MODE0: h1[CAP][FD]; MODE1: h2[CAP][HD]
    const int Kdim, const int NN)
{
  const int nt_total = meta[32 + MODE];
  const int mt = blockIdx.x;
  if (mt >= nt_total) return;
  const int* tmap = meta + (MODE == 0 ? 64 : 256);
  const int e = tmap[mt * 2], arow0 = tmap[mt * 2 + 1];
  const int ne_end = meta[16 + e] + meta[e];
  const int n0 = blockIdx.y * BN;

  __shared__ unsigned short lA[BM * BK];
  __shared__ unsigned short lB[BN * BK];

  const int tid = threadIdx.x;
  const int wave = tid >> 6, lane = tid & 63;
  const int wr = wave >> 1, wc = wave & 1;
  constexpr int FM = BM / 32, FN = BN / 32;
  constexpr int NCA = BM / 32;   // A 1KB-chunks per wave
  constexpr int NCB = BN / 32;   // B chunks per wave

  // swizzled k-offset for staging: logical chunk (lane&7) XOR row-in-8 (lane>>3)&7
  const int kswz = ((lane & 7) ^ ((lane >> 3) & 7)) * 8;

  size_t aSrc[NCA];
#pragma unroll
  for (int i = 0; i < NCA; ++i) {
    int c = wave + i * 4;
    int r = c * 8 + (lane >> 3);
    int grow = (MODE == 0) ? token_list[arow0 + r] : (arow0 + r);
    aSrc[i] = (size_t)grow * Kdim + kswz;
  }
  size_t bSrc[NCB];
#pragma unroll
  for (int i = 0; i < NCB; ++i) {
    int c = wave + i * 4;
    int n = n0 + c * 8 + (lane >> 3);
    bSrc[i] = ((size_t)e * NN + n) * Kdim + kswz;
  }

  f32x4 acc[FM][FN] = {};

  for (int k0 = 0; k0 < Kdim; k0 += BK) {
#pragma unroll
    for (int i = 0; i < NCA; ++i)
      gload_lds16(A + aSrc[i] + k0, &lA[(wave + i * 4) * 512]);
#pragma unroll
    for (int i = 0; i < NCB; ++i)
      gload_lds16(Bw + bSrc[i] + k0, &lB[(wave + i * 4) * 512]);
    __syncthreads();
#pragma unroll
    for (int kk = 0; kk < BK; kk += 32) {
      bf16x8 af[FM], bfr[FN];
      const int lc = (kk >> 3) + (lane >> 4);   // logical 16B-chunk index 0..7
#pragma unroll
      for (int m2 = 0; m2 < FM; ++m2) {
        int row = wr * (BM / 2) + m2 * 16 + (lane & 15);
        af[m2] = *(const bf16x8*)&lA[row * BK + ((lc ^ (row & 7)) << 3)];
      }
#pragma unroll
      for (int n2 = 0; n2 < FN; ++n2) {
        int row = wc * (BN / 2) + n2 * 16 + (lane & 15);
        bfr[n2] = *(const bf16x8*)&lB[row * BK + ((lc ^ (row & 7)) << 3)];
      }
#pragma unroll
      for (int m2 = 0; m2 < FM; ++m2)
#pragma unroll
        for (int n2 = 0; n2 < FN; ++n2)
          acc[m2][n2] = __builtin_amdgcn_mfma_f32_16x16x32_bf16(
              af[m2], bfr[n2], acc[m2][n2], 0, 0, 0);
    }
    __syncthreads();
  }

  const float* be = bias + (size_t)e * NN;
#pragma unroll
  for (int m2 = 0; m2 < FM; ++m2) {
    const int lr = wr * (BM / 2) + m2 * 16 + (lane >> 4) * 4;
#pragma unroll
    for (int n2 = 0; n2 < FN; ++n2) {
      const int col = n0 + wc * (BN / 2) + n2 * 16 + (lane & 15);
      const float bv = be[col];
#pragma unroll
      for (int j = 0; j < 4; ++j) {
        const int arow = arow0 + lr + j;
        if (arow < ne_end) {
          float v = acc[m2][n2][j] + bv;
          if (MODE == 0) { v = fmaxf(v, 0.f); v = v * v; }
          Cout[(size_t)arow * NN + col] = f2bf(v);
        }
      }
    }
  }
}

// ---------------- combine: out[t] = g0*h2[p0] + g1*h2[p1] ----------------------
__global__ __launch_bounds__(256) void combine_kernel(
    const unsigned short* __restrict__ h2, const int* __restrict__ pos_list,
    const float* __restrict__ gates, float* __restrict__ out)
{
  const int wave = threadIdx.x >> 6, lane = threadIdx.x & 63;
  const int t = blockIdx.x * 4 + wave;
  const int p0 = pos_list[2 * t], p1 = pos_list[2 * t + 1];
  const float g0 = gates[2 * t], g1 = gates[2 * t + 1];
  const unsigned short* r0 = h2 + (size_t)p0 * HD;
  const unsigned short* r1 = h2 + (size_t)p1 * HD;
  float* o = out + (size_t)t * HD;
#pragma unroll
  for (int i = 0; i < 3; ++i) {
    int h = i * 256 + lane * 4;
    ushort4 a = *(const ushort4*)&r0[h];
    ushort4 b = *(const ushort4*)&r1[h];
    float4 o4;
    o4.x = g0 * bf2f(a.x) + g1 * bf2f(b.x);
    o4.y = g0 * bf2f(a.y) + g1 * bf2f(b.y);
    o4.z = g0 * bf2f(a.z) + g1 * bf2f(b.z);
    o4.w = g0 * bf2f(a.w) + g1 * bf2f(b.w);
    *(float4*)&o[h] = o4;
  }
}

// -------------------------------- launch ---------------------------------------
extern "C" void kernel_launch(void* const* d_in, const int* in_sizes, int n_in,
                              void* d_out, int out_size, void* d_ws, size_t ws_size,
                              hipStream_t stream)
{
  (void)in_sizes; (void)n_in; (void)ws_size; (void)out_size;
  const float* x  = (const float*)d_in[0];
  const float* rw = (const float*)d_in[1];
  const float* rb = (const float*)d_in[2];
  const float* w1 = (const float*)d_in[3];
  const float* b1 = (const float*)d_in[4];
  const float* w2 = (const float*)d_in[5];
  const float* b2 = (const float*)d_in[6];
  float* out = (float*)d_out;

  char* ws = (char*)d_ws;
  size_t off = 0;
  auto alloc = [&](size_t bytes) {
    off = (off + 255) & ~(size_t)255;
    void* p = ws + off;
    off += bytes;
    return p;
  };
  unsigned short* xb  = (unsigned short*)alloc((size_t)TOK * HD * 2);
  unsigned short* w1t = (unsigned short*)alloc((size_t)E_EXP * FD * HD * 2);
  unsigned short* w2t = (unsigned short*)alloc((size_t)E_EXP * HD * FD * 2);
  unsigned short* h1  = (unsigned short*)alloc((size_t)CAP * FD * 2);
  unsigned short* h2  = (unsigned short*)alloc((size_t)CAP * HD * 2);
  int*   token_list = (int*)alloc(CAP * 4);
  int*   pos_list   = (int*)alloc((size_t)TOK * 2 * 4);
  int*   ids        = (int*)alloc((size_t)TOK * 2 * 4);
  float* gates      = (float*)alloc((size_t)TOK * 2 * 4);
  float* probs      = (float*)alloc((size_t)TOK * 8 * 4);
  int*   meta       = (int*)alloc(1024 * 4);
  char*  ctrl       = (char*)token_list;
  size_t ctrl_bytes = (ws + off) - ctrl;

  hipMemsetAsync(ctrl, 0, ctrl_bytes, stream);

  router_kernel<<<TOK / 4, 256, 0, stream>>>(x, rw, rb, xb, probs, ids, gates);
  transpose_kernel<<<dim3(FD / 32, HD / 32, E_EXP), 256, 0, stream>>>(w1, w1t, HD, FD);
  transpose_kernel<<<dim3(HD / 32, FD / 32, E_EXP), 256, 0, stream>>>(w2, w2t, FD, HD);
  stats_kernel<<<1, 256, 0, stream>>>(ids, probs, meta, out + (size_t)TOK * HD);
  scatter_kernel<<<TOK / 256, 256, 0, stream>>>(ids, meta, token_list, pos_list);
  moe_gemm<128, 128, 0><<<dim3(71, FD / 128), 256, 0, stream>>>(
      xb, w1t, b1, token_list, meta, h1, HD, FD);
  moe_gemm<64, 256, 1><<<dim3(135, HD / 256), 256, 0, stream>>>(
      h1, w2t, b2, token_list, meta, h2, FD, HD);
  combine_kernel<<<TOK / 4, 256, 0, stream>>>(h2, pos_list, gates, out);
}